// Round 9
// baseline (486.207 us; speedup 1.0000x reference)
//
#include <hip/hip_runtime.h>
#include <hip/hip_bf16.h>
#include <stdint.h>

typedef float f32x4 __attribute__((ext_vector_type(4)));
typedef int i32x4 __attribute__((ext_vector_type(4)));

// ---------------- async global -> LDS (16B/lane, wave-uniform LDS base) ----------------
__device__ __forceinline__ void gload_lds16(const signed char* g, signed char* l) {
    __builtin_amdgcn_global_load_lds(
        (const __attribute__((address_space(1))) unsigned int*)g,
        (__attribute__((address_space(3))) unsigned int*)l,
        16, 0, 0);
}

// ---------------- per-row activation quantization: f32 -> i8, qrow = amax/127 ----------------
__global__ __launch_bounds__(256) void quant_rows_kernel(
        const float* __restrict__ A, signed char* __restrict__ Aq,
        float* __restrict__ qrow, int K) {
    const long row = blockIdx.x;
    const float* a = A + row * (long)K;
    signed char* o = Aq + row * (long)K;
    const int tid = threadIdx.x;
    const int nch = K >> 2;                       // f32x4 chunks per row
    float amax = 0.f;
    for (int c = tid; c < nch; c += 256) {
        f32x4 v = ((const f32x4*)a)[c];
        amax = fmaxf(amax, fmaxf(fmaxf(fabsf(v[0]), fabsf(v[1])),
                                 fmaxf(fabsf(v[2]), fabsf(v[3]))));
    }
#pragma unroll
    for (int off = 32; off; off >>= 1)
        amax = fmaxf(amax, __shfl_xor(amax, off, 64));
    __shared__ float red[4];
    if ((tid & 63) == 0) red[tid >> 6] = amax;
    __syncthreads();
    amax = fmaxf(fmaxf(red[0], red[1]), fmaxf(red[2], red[3]));
    const float s = amax > 0.f ? 127.f / amax : 0.f;
    if (tid == 0) qrow[row] = amax > 0.f ? amax / 127.f : 0.f;
    for (int c = tid; c < nch; c += 256) {       // second sweep: row is L1/L2-hot
        f32x4 v = ((const f32x4*)a)[c];
        int r = 0;
#pragma unroll
        for (int i = 0; i < 4; ++i) {
            int q = (int)__builtin_rintf(v[i] * s);
            r |= (q & 0xff) << (8 * i);
        }
        ((int*)o)[c] = r;
    }
}

// ---------------- weight conversion: i32 (int8-range) -> i8, exact ----------------
__global__ __launch_bounds__(256) void cvt_i32_i8_kernel(
        const int* __restrict__ in, signed char* __restrict__ out, long n) {
    long base = ((long)blockIdx.x * 256 + threadIdx.x) * 16;
    long stride = (long)gridDim.x * 256 * 16;
    for (long i = base; i < n; i += stride) {
        i32x4 pk;
#pragma unroll
        for (int c = 0; c < 4; ++c) {
            i32x4 v = *(const i32x4*)(in + i + c * 4);
            pk[c] = (v[0] & 0xff) | ((v[1] & 0xff) << 8) |
                    ((v[2] & 0xff) << 16) | ((v[3] & 0xff) << 24);
        }
        *(i32x4*)(out + i) = pk;
    }
}

// =====================================================================
// 256x256 i8 GEMM, BK=64, 4-phase/2-K-tiles (fat phases):
// phase = {barrier; lgkm0(prev reads); reads_{next}; stages; 16 MFMA; [vmcnt]}.
// Fences: VM1 @ph1/ph3 ends (hazard ledger: steady-state outstanding=4).
// LDS 64 KiB: region(buf,op,half) = buf*32768 + op*16384 + half*8192 B,
// each region = 128 rows x 64 cols i8, 64-B rows,
// swizzle: LDS[row][slot16B] holds global k-chunk slot ^ ((row>>1)&3).
// =====================================================================

template<int BUF, int MH>
__device__ __forceinline__ void readAf(const signed char* smem, i32x4 (&fa)[4],
                                       const int (&off)[4]) {
    const signed char* rg = smem + BUF * 32768 + MH * 8192;
#pragma unroll
    for (int ml = 0; ml < 4; ++ml)
        fa[ml] = *(const i32x4*)(rg + off[ml]);
}

// read B both NH halves: fb[NH*2+nl]
template<int BUF>
__device__ __forceinline__ void readBf2(const signed char* smem, i32x4 (&fb)[4],
                                        const int (&off)[2]) {
#pragma unroll
    for (int nh = 0; nh < 2; ++nh) {
        const signed char* rg = smem + BUF * 32768 + 16384 + nh * 8192;
#pragma unroll
        for (int nl = 0; nl < 2; ++nl)
            fb[nh * 2 + nl] = *(const i32x4*)(rg + off[nl]);
    }
}

// 16 MFMAs: one MH half x all 4 N-fragments
template<int MH>
__device__ __forceinline__ void mfmas2(i32x4 (&acc)[8][4],
                                       const i32x4 (&fa)[4], const i32x4 (&fb)[4]) {
#pragma unroll
    for (int ml = 0; ml < 4; ++ml)
#pragma unroll
        for (int nf = 0; nf < 4; ++nf)
            acc[MH * 4 + ml][nf] = __builtin_amdgcn_mfma_i32_16x16x64_i8(
                fa[ml], fb[nf], acc[MH * 4 + ml][nf], 0, 0, 0);
}

#define BARw()  __builtin_amdgcn_s_barrier()
#define LG0()   { asm volatile("s_waitcnt lgkmcnt(0)" ::: "memory"); \
                  __builtin_amdgcn_sched_barrier(0); }
#define SB0()   __builtin_amdgcn_sched_barrier(0)
#define P1()    __builtin_amdgcn_s_setprio(1)
#define P0()    __builtin_amdgcn_s_setprio(0)
#define VM1()   asm volatile("s_waitcnt vmcnt(1)" ::: "memory")
#define VM4()   asm volatile("s_waitcnt vmcnt(4)" ::: "memory")
#define VM0()   asm volatile("s_waitcnt vmcnt(0)" ::: "memory")

__global__ __launch_bounds__(512, 1) void gemm_i8_4phase(
        const signed char* __restrict__ A,      // [M][K] i8
        const signed char* __restrict__ W,      // [N][K] i8
        const float* __restrict__ qrow,         // [M] row dequant scale
        const float* __restrict__ scales,       // [N]
        const float* __restrict__ bias,         // [N]
        float* __restrict__ C,                  // [M][N]
        int M, int N, int K) {
    extern __shared__ signed char smem[];       // 65536 B

    const int tid  = threadIdx.x;
    const int lane = tid & 63;
    const int wid  = tid >> 6;
    const int wr = wid >> 2;     // 0..1
    const int wc = wid & 3;      // 0..3
    const int fr = lane & 15;
    const int fq = lane >> 4;
    const int kg = lane >> 4;

    const int nwg = gridDim.x;
    const int bid = blockIdx.x;
    const int swz = ((nwg & 7) == 0) ? ((bid & 7) * (nwg >> 3) + (bid >> 3)) : bid;
    const int tiles_n = N >> 8;
    const int tm = swz / tiles_n;
    const int tn = swz % tiles_n;
    const int arow = tm << 8;
    const int brow = tn << 8;

    // ---- thread-constant LDS read byte-offsets within a region
    int aRd[4], bRd[2];
#pragma unroll
    for (int ml = 0; ml < 4; ++ml) {
        const int lrow = wr * 16 + ml * 32 + fr;
        aRd[ml] = lrow * 64 + ((kg ^ ((lrow >> 1) & 3)) << 4);
    }
#pragma unroll
    for (int nl = 0; nl < 2; ++nl) {
        const int lrow = wc * 16 + nl * 64 + fr;
        bRd[nl] = lrow * 64 + ((kg ^ ((lrow >> 1) & 3)) << 4);
    }

    // ---- thread-constant stage offsets (32-bit, i8 elements == bytes)
    const int srow = tid >> 2;
    const int sswz = (((tid & 3) ^ ((srow >> 1) & 3)) << 4);   // pre-swizzled source col
    int aOff[2], wOff[2];
#pragma unroll
    for (int h = 0; h < 2; ++h) {
        aOff[h] = (arow + h * 128 + srow) * K + sswz;
        wOff[h] = (brow + h * 128 + srow) * K + sswz;
    }
    const int ldsSt = wid * 1024;

#define STA(kt, h) gload_lds16(A + aOff[h] + (kt) * 64, \
                               smem + ((kt) & 1) * 32768 + (h) * 8192 + ldsSt)
#define STB(kt, h) gload_lds16(W + wOff[h] + (kt) * 64, \
                               smem + ((kt) & 1) * 32768 + 16384 + (h) * 8192 + ldsSt)

    i32x4 acc[8][4] = {};
    i32x4 aX[4], aY[4], bX[4], bY[4];

    const int NT = K >> 6;       // K-tiles of 64; NT even, >= 4

    // ---- prologue: stage tiles 0 (buf0) and 1 (buf1) fully; read ph1 frags
    STA(0, 0); STB(0, 0); STA(0, 1); STB(0, 1);
    STA(1, 0); STB(1, 0); STA(1, 1); STB(1, 1);
    VM4();                                      // tile0's 4 stages landed
    BARw();
    readAf<0, 0>(smem, aX, aRd);                // A(tile0, MH0)
    readBf2<0>(smem, bX, bRd);                  // B(tile0)

    // ---- main loop: consume tiles a=2i (buf0), b=2i+1 (buf1); stage c,d
    for (int i = 0; i < (NT >> 1) - 1; ++i) {
        const int c = 2 * i + 2, d = 2 * i + 3;
        // PH1: MFMA(a, MH0)
        BARw(); LG0();
        readAf<0, 1>(smem, aY, aRd);            // A(a, MH1)
        STA(c, 0); SB0();
        P1(); mfmas2<0>(acc, aX, bX); P0();
        VM1();                                  // tile b (4 oldest) fully landed
        // PH2: MFMA(a, MH1)
        BARw(); LG0();
        readAf<1, 0>(smem, aX, aRd);            // A(b, MH0)
        readBf2<1>(smem, bY, bRd);              // B(b)
        STA(c, 1); STB(c, 0); SB0();
        P1(); mfmas2<1>(acc, aY, bX); P0();
        // PH3: MFMA(b, MH0)
        BARw(); LG0();
        readAf<1, 1>(smem, aY, aRd);            // A(b, MH1)
        STB(c, 1); STA(d, 0); SB0();
        P1(); mfmas2<0>(acc, aX, bY); P0();
        VM1();                                  // tile c (4 oldest) fully landed
        // PH4: MFMA(b, MH1)
        BARw(); LG0();
        readAf<0, 0>(smem, aX, aRd);            // A(c, MH0)
        readBf2<0>(smem, bX, bRd);              // B(c)
        STA(d, 1); STB(d, 0); STB(d, 1); SB0();
        P1(); mfmas2<1>(acc, aY, bY); P0();
    }

    // ---- epilogue: tiles NT-2 (buf0), NT-1 (buf1); no staging
    // E1
    BARw(); LG0();
    readAf<0, 1>(smem, aY, aRd); SB0();
    P1(); mfmas2<0>(acc, aX, bX); P0();
    VM0();                                      // tile NT-1 fully landed
    // E2
    BARw(); LG0();
    readAf<1, 0>(smem, aX, aRd);
    readBf2<1>(smem, bY, bRd); SB0();
    P1(); mfmas2<1>(acc, aY, bX); P0();
    // E3
    BARw(); LG0();
    readAf<1, 1>(smem, aY, aRd); SB0();
    P1(); mfmas2<0>(acc, aX, bY); P0();
    // E4
    BARw(); LG0();
    P1(); mfmas2<1>(acc, aY, bY); P0();

#undef STA
#undef STB

    // ---- dequant row scales for this thread's 32 output rows
    float qr[8][4];
#pragma unroll
    for (int mh = 0; mh < 2; ++mh)
#pragma unroll
        for (int ml = 0; ml < 4; ++ml) {
            const int row0 = arow + wr * 16 + mh * 128 + ml * 32 + fq * 4;
#pragma unroll
            for (int j = 0; j < 4; ++j)
                qr[mh * 4 + ml][j] = qrow[row0 + j];
        }

    // ---- C write: out = acc * qrow[row] * scales[col] + bias[col]
    // 16x16 C/D layout: col = lane&15, row = (lane>>4)*4 + reg
#pragma unroll
    for (int n = 0; n < 4; ++n) {
        const int col = tn * 256 + wc * 16 + n * 64 + fr;
        const float s = scales[col];
        const float bb = bias[col];
#pragma unroll
        for (int mh = 0; mh < 2; ++mh)
#pragma unroll
            for (int ml = 0; ml < 4; ++ml) {
                const int m = mh * 4 + ml;
                const int row0 = arow + wr * 16 + mh * 128 + ml * 32 + fq * 4;
#pragma unroll
                for (int j = 0; j < 4; ++j)
                    C[(long)(row0 + j) * N + col] =
                        (float)acc[m][n][j] * (qr[m][j] * s) + bb;
            }
    }
}

// ---------------- fallback: plain fp32 (odd shapes / tiny ws only) ----------------
__global__ __launch_bounds__(256) void gemm_fallback_kernel(
        const float* __restrict__ A, const int* __restrict__ W,
        const float* __restrict__ scales, const float* __restrict__ bias,
        float* __restrict__ C, int M, int N, int K) {
    __shared__ float As[64][16];
    __shared__ float Ws[64][16];
    const int tiles_n = N / 64;
    const int tm = blockIdx.x / tiles_n, tn = blockIdx.x % tiles_n;
    const int tid = threadIdx.x, tx = tid & 15, ty = tid >> 4;
    float acc[4][4] = {};
    for (int k0 = 0; k0 < K; k0 += 16) {
        __syncthreads();
#pragma unroll
        for (int i = 0; i < 4; ++i) {
            const int idx = tid + i * 256;
            const int r = idx >> 4, c = idx & 15;
            As[r][c] = A[(long)(tm * 64 + r) * K + k0 + c];
            Ws[r][c] = (float)W[(long)(tn * 64 + r) * K + k0 + c];
        }
        __syncthreads();
#pragma unroll
        for (int kk = 0; kk < 16; ++kk) {
            float a[4], w[4];
#pragma unroll
            for (int r = 0; r < 4; ++r) a[r] = As[ty * 4 + r][kk];
#pragma unroll
            for (int c = 0; c < 4; ++c) w[c] = Ws[tx * 4 + c][kk];
#pragma unroll
            for (int r = 0; r < 4; ++r)
#pragma unroll
                for (int c = 0; c < 4; ++c) acc[r][c] += a[r] * w[c];
        }
    }
#pragma unroll
    for (int r = 0; r < 4; ++r)
#pragma unroll
        for (int c = 0; c < 4; ++c) {
            const int col = tn * 64 + tx * 4 + c;
            C[(long)(tm * 64 + ty * 4 + r) * N + col] = acc[r][c] * scales[col] + bias[col];
        }
}

extern "C" void kernel_launch(void* const* d_in, const int* in_sizes, int n_in,
                              void* d_out, int out_size, void* d_ws, size_t ws_size,
                              hipStream_t stream) {
    const float* A32    = (const float*)d_in[0];
    const int*   Wq     = (const int*)d_in[1];
    const float* scales = (const float*)d_in[2];
    const float* bias   = (const float*)d_in[3];
    float* C = (float*)d_out;

    const long aElems = in_sizes[0];        // M*K
    const long wElems = in_sizes[1];        // N*K
    const int  N = in_sizes[2];
    const int  K = (int)(wElems / N);
    const int  M = (int)(aElems / K);

    const size_t need = (size_t)aElems + (size_t)wElems + (size_t)M * 4 + 64;
    const bool div256 = (M % 256 == 0) && (N % 256 == 0) && (K % 128 == 0) && (K >= 256) &&
                        ((long)M * K < 2000000000L) && ((long)N * K < 2000000000L);

    if (ws_size >= need && div256) {
        signed char* Aq  = (signed char*)d_ws;
        signed char* Wq8 = Aq + aElems;
        float* qrow = (float*)(Wq8 + wElems);
        quant_rows_kernel<<<M, 256, 0, stream>>>(A32, Aq, qrow, K);
        cvt_i32_i8_kernel<<<2048, 256, 0, stream>>>(Wq, Wq8, wElems);
        const int nwg = (M / 256) * (N / 256);
        gemm_i8_4phase<<<nwg, 512, 65536, stream>>>(Aq, Wq8, qrow, scales, bias, C, M, N, K);
    } else {
        const int nwg = (M / 64) * (N / 64);
        gemm_fallback_kernel<<<nwg, 256, 0, stream>>>(A32, Wq, scales, bias, C, M, N, K);
    }
}